// Round 2
// baseline (268.612 us; speedup 1.0000x reference)
//
#include <hip/hip_runtime.h>
#include <hip/hip_bf16.h>

#define VOCAB 128000
#define BATCH 256
#define NTHREADS 1024

// One block per batch row. Streams the row once, tracking running
// (max value, first index). Sampled rows: val = logits*invT - log(noise)
// (monotonic equivalent of softmax(logits/t)/noise). Greedy rows (t==0):
// val = logits, and noise is never read (saves ~25% of HBM traffic).
// Output dtype is int32 (argmax indices) — the harness reads d_out as int32.
__global__ __launch_bounds__(NTHREADS) void sampler_kernel(
    const float* __restrict__ logits,
    const float* __restrict__ temps,
    const float* __restrict__ noise,
    int* __restrict__ out)
{
    const int row  = blockIdx.x;
    const int tid  = threadIdx.x;
    const float t  = temps[row];
    const bool greedy = (t == 0.0f);
    const float invT  = greedy ? 1.0f : (1.0f / t);

    const float4* __restrict__ lg4 = (const float4*)(logits + (size_t)row * VOCAB);
    const float4* __restrict__ nz4 = (const float4*)(noise  + (size_t)row * VOCAB);
    const int nvec = VOCAB / 4;  // 32000

    float best = -INFINITY;
    int   bidx = 0x7fffffff;

    if (greedy) {
        // argmax(logits), first occurrence on ties
        for (int v = tid; v < nvec; v += NTHREADS) {
            float4 l = lg4[v];
            int base = v * 4;
            if (l.x > best) { best = l.x; bidx = base;     }
            if (l.y > best) { best = l.y; bidx = base + 1; }
            if (l.z > best) { best = l.z; bidx = base + 2; }
            if (l.w > best) { best = l.w; bidx = base + 3; }
        }
    } else {
        // argmax(logits/t - log(noise))
        for (int v = tid; v < nvec; v += NTHREADS) {
            float4 l = lg4[v];
            float4 n = nz4[v];
            int base = v * 4;
            float vx = l.x * invT - __logf(n.x);
            float vy = l.y * invT - __logf(n.y);
            float vz = l.z * invT - __logf(n.z);
            float vw = l.w * invT - __logf(n.w);
            if (vx > best) { best = vx; bidx = base;     }
            if (vy > best) { best = vy; bidx = base + 1; }
            if (vz > best) { best = vz; bidx = base + 2; }
            if (vw > best) { best = vw; bidx = base + 3; }
        }
    }

    // Wave-level butterfly reduce: (max value, min index on tie)
    #pragma unroll
    for (int off = 32; off > 0; off >>= 1) {
        float ov = __shfl_xor(best, off, 64);
        int   oi = __shfl_xor(bidx, off, 64);
        if (ov > best || (ov == best && oi < bidx)) { best = ov; bidx = oi; }
    }

    // Cross-wave reduce via LDS (16 waves)
    __shared__ float sv[NTHREADS / 64];
    __shared__ int   si[NTHREADS / 64];
    const int wave = tid >> 6;
    const int lane = tid & 63;
    if (lane == 0) { sv[wave] = best; si[wave] = bidx; }
    __syncthreads();

    if (tid == 0) {
        float b  = sv[0];
        int   bi = si[0];
        #pragma unroll
        for (int w = 1; w < NTHREADS / 64; ++w) {
            float ov = sv[w]; int oi = si[w];
            if (ov > b || (ov == b && oi < bi)) { b = ov; bi = oi; }
        }
        out[row] = bi;
    }
}

extern "C" void kernel_launch(void* const* d_in, const int* in_sizes, int n_in,
                              void* d_out, int out_size, void* d_ws, size_t ws_size,
                              hipStream_t stream) {
    const float* logits = (const float*)d_in[0];
    const float* temps  = (const float*)d_in[1];
    const float* noise  = (const float*)d_in[2];
    int* out = (int*)d_out;

    sampler_kernel<<<BATCH, NTHREADS, 0, stream>>>(logits, temps, noise, out);
}